// Round 15
// baseline (91.797 us; speedup 1.0000x reference)
//
#include <hip/hip_runtime.h>
#include <math.h>

// ---------------------------------------------------------------------------
// B=1024. R15: K-split. k1 = conv+G1-half per (batch,half) over 2048 blocks
// (21.8KB LDS -> 7 blocks/CU = 28 waves/CU), raw fp32 partials to ws.
// k2 = sum partials + epilogue + R13-exact tail (1024 blocks).
//   reshape fact: node n = (c*62+r)/32, feature f = ((c*62+r)%32)*15 + j
//   G1 K-order permuted: k' = pj*32 + s; W table padded to 16 kc (kc15 = 0)
//   conv via mfma_32x32x16_f16 (32 pos x 32 ch), 3 K-chunks, b128 tap loads
//   tail: 3x SOGC all-fp16-MFMA; transposed-S softmax (row-per-lane).
// ---------------------------------------------------------------------------

typedef _Float16 f16x8 __attribute__((ext_vector_type(8)));
typedef float    f32x4  __attribute__((ext_vector_type(4)));
typedef float    f32x16 __attribute__((ext_vector_type(16)));

__device__ __forceinline__ unsigned short f32_to_f16u(float f) {
    const _Float16 h = (_Float16)f;
    return __builtin_bit_cast(unsigned short, h);
}
__device__ __forceinline__ float f16u_to_f32(unsigned short u) {
    return (float)__builtin_bit_cast(_Float16, u);
}
__device__ __forceinline__ float fast_tanh(float v) {
    v = fminf(fmaxf(v, -15.f), 15.f);
    const float ex = __expf(2.f * v);
    return (ex - 1.f) / (ex + 1.f);
}

// ws layout:
//   u16 [0, 49152)        G1 W fp16, 16 kc (kc=15 zeros), k'=pj*32+s
//   u16 [92160, 93696)    conv W frags fp16 (32x32 shape, 3 chunks)
//   u16 [94208, 100352)   stage2 + stage3 B-frag fp16 [col 96][k 32]
//   byte 204800 ...       partials: f32x4[(b*2+h)*1536 + nt*256 + tid]
#define PART_OFF 204800

// ============================ prepack ======================================
__global__ __launch_bounds__(256) void prepack_kernel(
    const float* __restrict__ bnw1, const float* __restrict__ gw1,
    const float* __restrict__ cw,
    const float* __restrict__ bnw2, const float* __restrict__ gw2,
    const float* __restrict__ bnw3, const float* __restrict__ gw3,
    unsigned short* __restrict__ wp)
{
    const int idx = blockIdx.x * 256 + threadIdx.x;   // grid covers 100352
    if (idx < 49152) {
        const int kc = idx / 3072, r = idx - kc * 3072;
        const int q = r / 768, r2 = r - q * 768;
        const int col = r2 >> 3, j = r2 & 7;
        float w = 0.f;
        if (kc < 15) {
            const int s = q * 8 + j;
            const int ko = s * 15 + kc;
            w = (col < 64) ? bnw1[ko * 64 + col] : gw1[ko * 32 + (col - 64)];
        }
        wp[idx] = f32_to_f16u(w);
    } else if (idx >= 92160 && idx < 93696) {
        const int e = idx - 92160;
        const int c = e >> 9, l = (e >> 3) & 63, j = e & 7;
        const int ch = l & 31, dio = l >> 5;
        const int di = (c < 2) ? (2 * c + dio) : (4 + dio);
        const float w = (j < 5 && di < 5) ? cw[ch * 25 + di * 5 + j] : 0.f;
        wp[idx] = f32_to_f16u(w);
    } else if (idx >= 94208 && idx < 100352) {
        const int e2 = idx - 94208;
        const int s = e2 / 3072, r = e2 - s * 3072;
        const int col = r >> 5, k = r & 31;
        const float* bnw = s ? bnw3 : bnw2;
        const float* gw  = s ? gw3  : gw2;
        const float w = (col < 64) ? bnw[k * 64 + col] : gw[k * 32 + (col - 64)];
        wp[idx] = f32_to_f16u(w);
    }
}

// ================= k1: conv + G1 half (per batch, half) ====================
__global__ __launch_bounds__(256, 7) void conv_g1_kernel(
    const float* __restrict__ x,     // (B,66,64)
    const float* __restrict__ cb,    // (32,)
    const unsigned short* __restrict__ wp,
    float4* __restrict__ part)       // partial acc
{
    // LDS: xbs [68][40] f16 = 5440 B @0 | Xcol @5440 [64][128] u16 = 16384 B
    __shared__ __align__(16) char lds[21824];
    unsigned short* xbs  = (unsigned short*)lds;
    unsigned short* Xcol = (unsigned short*)(lds + 5440);

    const int bx = blockIdx.x;
    const int b = bx >> 1, h = bx & 1;
    const int tid = threadIdx.x;
    const int wv = tid >> 6, ln = tid & 63;

    // ---- phase A: x col-slice [h*32, h*32+40) -> f16 LDS; pads zero ----
    const float* xgf = x + (size_t)b * 4224;
    for (int idx = tid; idx < 680; idx += 256) {        // 68 rows x 10 f4-groups
        const int row = idx / 10, c4 = idx - (idx / 10) * 10;
        const int col = h * 32 + c4 * 4;
        short4 s;
        if (row < 66 && col < 64) {
            const float4 v = *(const float4*)(xgf + row * 64 + col);
            s.x = (short)f32_to_f16u(v.x);
            s.y = (short)f32_to_f16u(v.y);
            s.z = (short)f32_to_f16u(v.z);
            s.w = (short)f32_to_f16u(v.w);
        } else { s.x = 0; s.y = 0; s.z = 0; s.w = 0; }
        *(short4*)(xbs + row * 40 + c4 * 4) = s;
    }
    if (tid < 128)                                      // Xcol rows 62,63 zero
        ((unsigned int*)(Xcol + 62 * 128))[tid] = 0u;
    __syncthreads();

    // conv lane roles: ch=l&31, hi=l>>5; A: m=l&15, rp=(l>>4)&1, dio=l>>5
    const int m = ln & 15, rp = (ln >> 4) & 1, dio = ln >> 5;
    const int ch = ln & 31, hi = ln >> 5;
    f16x8 Wc[3];
    #pragma unroll
    for (int c = 0; c < 3; ++c)
        Wc[c] = *(const f16x8*)(wp + 92160 + c * 512 + ln * 8);
    const float cbv = cb[ch];
    const f32x16 z16 = {};

    // G1 lane roles: rt = l&15, q = l>>4
    const int rt = ln & 15, q = ln >> 4;
    f32x4 acc[6];
    #pragma unroll
    for (int nt = 0; nt < 6; ++nt) acc[nt] = (f32x4){0.f, 0.f, 0.f, 0.f};

    for (int pp = 0; pp < 2; ++pp) {
        const int pjg = h * 2 + pp;
        const int j0s = pp * 16;                        // slice-local col base
        // prefetch g=0 G1 B-frags
        f16x8 Bp[6];
        {
            const unsigned short* wB = wp + (pjg * 4) * 3072 + q * 768 + rt * 8;
            #pragma unroll
            for (int nt = 0; nt < 6; ++nt) Bp[nt] = *(const f16x8*)(wB + nt * 128);
        }
        // ---- conv: 31 row-pairs, pooled cols pjg*4 + {0..3} -> Xcol ----
        #pragma unroll 4
        for (int p = wv; p < 31; p += 4) {
            const int r0 = 2 * p;
            const unsigned short* base = xbs + (r0 + rp + dio) * 40 + j0s + m;
            f32x16 a32;
            #pragma unroll
            for (int c = 0; c < 3; ++c) {
                const f16x8 Af = *(const f16x8*)(base + c * 80);  // 2 rows x 40
                a32 = __builtin_amdgcn_mfma_f32_32x32x16_f16(
                          Af, Wc[c], (c == 0) ? z16 : a32, 0, 0, 0);
            }
            #pragma unroll
            for (int i = 0; i < 4; ++i) {
                const int t = 2 * i + hi;
                const int rpo = t >> 2, g = t & 3;
                float v = fmaxf(fmaxf(fmaxf(fmaxf(
                              a32[4 * i], a32[4 * i + 1]), a32[4 * i + 2]),
                              a32[4 * i + 3]) + cbv, 0.f);
                // pjg==3,g==3 dead slot feeds kc=15 (zero W) -> write always
                const int row = r0 + rpo;
                const int tt = ch * 62 + row;            // n = tt/32, s = tt%32
                const int n = tt >> 5, sf = tt & 31;
                Xcol[n * 128 + ((g * 32 + sf) ^ ((n & 7) << 3))] =
                    f32_to_f16u(v);
            }
        }
        __syncthreads();
        // ---- G1: kc = pjg*4 + g; 1-deep B pipeline ----
        {
            const int row = wv * 16 + rt;
            #pragma unroll
            for (int g = 0; g < 4; ++g) {
                f16x8 Bn[6];
                #pragma unroll
                for (int nt = 0; nt < 6; ++nt)
                    Bn[nt] = (g < 3)
                        ? *(const f16x8*)(wp + (pjg * 4 + g + 1) * 3072
                                          + q * 768 + nt * 128 + rt * 8)
                        : Bp[nt];
                const f16x8 A = *(const f16x8*)(
                    Xcol + row * 128 + (((g * 4 + q) ^ (row & 7)) << 3));
                #pragma unroll
                for (int nt = 0; nt < 6; ++nt)
                    acc[nt] = __builtin_amdgcn_mfma_f32_16x16x32_f16(A, Bp[nt], acc[nt], 0, 0, 0);
                #pragma unroll
                for (int nt = 0; nt < 6; ++nt) Bp[nt] = Bn[nt];
            }
        }
        __syncthreads();
    }

    // ---- store raw fp32 partials (coalesced f32x4, SoA over nt) ----
    {
        float4* dst = part + (size_t)bx * 1536;
        #pragma unroll
        for (int nt = 0; nt < 6; ++nt) {
            float4 v;
            v.x = acc[nt][0]; v.y = acc[nt][1];
            v.z = acc[nt][2]; v.w = acc[nt][3];
            dst[nt * 256 + tid] = v;
        }
    }
}

// ================= k2: sum partials + epilogue + tail ======================
__global__ __launch_bounds__(256, 4) void sogc_tail_kernel(
    const unsigned short* __restrict__ wp,
    const float4* __restrict__ part,
    const float* __restrict__ bnb1,  const float* __restrict__ gb1,
    const float* __restrict__ gb2,   const float* __restrict__ gb3,
    const float* __restrict__ bnb2,  const float* __restrict__ bnb3,
    const float* __restrict__ fcw,   const float* __restrict__ fcb,
    float* __restrict__ out)         // (B,3)
{
    // tail LDS: xaH u16@0 [64][72] | zB u16@4608 [32][72] | P u16@6912 [64][72]
    //           | xB u16@11520 [64][40] | degis @byte 28160
    __shared__ __align__(16) char lds[28416];
    unsigned short* xaH  = (unsigned short*)lds;
    unsigned short* zB   = xaH + 4608;
    unsigned short* P    = xaH + 6912;
    unsigned short* xB   = xaH + 11520;
    float* degis = (float*)(lds + 28160);

    const int b = blockIdx.x;
    const int tid = threadIdx.x;
    const int wv = tid >> 6, ln = tid & 63;
    const int rt = ln & 15, q = ln >> 4;

    // ---- load + sum partials ----
    f32x4 acc[6];
    {
        const float4* p0 = part + (size_t)(b * 2) * 1536;
        const float4* p1 = p0 + 1536;
        #pragma unroll
        for (int nt = 0; nt < 6; ++nt) {
            const float4 a = p0[nt * 256 + tid];
            const float4 c = p1[nt * 256 + tid];
            acc[nt][0] = a.x + c.x; acc[nt][1] = a.y + c.y;
            acc[nt][2] = a.z + c.z; acc[nt][3] = a.w + c.w;
        }
    }

    // ---- G1 epilogue -> tail LDS buffers ----
    {
        const int rq = wv * 4 + q;
        #pragma unroll
        for (int nt = 0; nt < 4; ++nt) {
            const float bb = bnb1[nt * 16 + rt];
            #pragma unroll
            for (int j = 0; j < 4; ++j) {
                const int r = rq * 4 + j;
                float th = fast_tanh(acc[nt][j] + bb);
                if (r >= 62) th = 0.f;
                xaH[r * 72 + nt * 16 + rt] = f32_to_f16u(th);
            }
        }
        #pragma unroll
        for (int nt = 4; nt < 6; ++nt) {
            const int o = (nt - 4) * 16 + rt;
            unsigned short zv[4];
            #pragma unroll
            for (int j = 0; j < 4; ++j) {
                const int r = rq * 4 + j;
                zv[j] = (r < 62) ? f32_to_f16u(acc[nt][j]) : (unsigned short)0;
            }
            *(ushort4*)(zB + o * 72 + rq * 4) =
                make_ushort4(zv[0], zv[1], zv[2], zv[3]);
        }
    }
    __syncthreads();

    // ---- tail: 3x SOGC all-fp16-MFMA, transposed-S softmax (R13-exact) ----
    const int c16 = ln & 15;
    const int r62 = wv * 16 + c16;
    const unsigned short* wstg = wp + 94208;

    #pragma unroll 1
    for (int st = 0; st < 3; ++st) {
        f16x8 zPre[2][2];
        #pragma unroll
        for (int kh = 0; kh < 2; ++kh) {
            const int chh = (kh * 4 + q) * 8;
            zPre[kh][0] = *(const f16x8*)(zB + c16 * 72 + chh);
            zPre[kh][1] = *(const f16x8*)(zB + (16 + c16) * 72 + chh);
        }
        f32x4 sacc[4];
        #pragma unroll
        for (int ct = 0; ct < 4; ++ct) sacc[ct] = (f32x4){0.f, 0.f, 0.f, 0.f};
        const int arow = r62 * 72;
        #pragma unroll
        for (int kh = 0; kh < 2; ++kh) {
            const int chh = (kh * 4 + q) * 8;
            const f16x8 Bw = *(const f16x8*)(xaH + arow + chh);
            #pragma unroll
            for (int ct = 0; ct < 4; ++ct) {
                const f16x8 Act = *(const f16x8*)(xaH + (ct * 16 + c16) * 72 + chh);
                sacc[ct] = __builtin_amdgcn_mfma_f32_16x16x32_f16(Act, Bw, sacc[ct], 0, 0, 0);
            }
        }
        f16x8 wbPre[6];
        if (st < 2) {
            const unsigned short* wsB = wstg + st * 3072;
            #pragma unroll
            for (int nt = 0; nt < 6; ++nt)
                wbPre[nt] = *(const f16x8*)(wsB + (nt * 16 + c16) * 32 + q * 8);
        }
        float mx = -1e30f;
        #pragma unroll
        for (int ct = 0; ct < 4; ++ct)
            #pragma unroll
            for (int j = 0; j < 4; ++j) mx = fmaxf(mx, sacc[ct][j]);
        mx = fmaxf(mx, __shfl_xor(mx, 16));
        mx = fmaxf(mx, __shfl_xor(mx, 32));
        float e[4][4];
        float sum = 0.f;
        #pragma unroll
        for (int ct = 0; ct < 4; ++ct)
            #pragma unroll
            for (int j = 0; j < 4; ++j) {
                float v = __expf(sacc[ct][j] - mx);
                if (ct == 3 && j >= 2 && q == 3) v = 0.f;    // cols 62,63
                e[ct][j] = v; sum += v;
            }
        sum += __shfl_xor(sum, 16);
        sum += __shfl_xor(sum, 32);
        const float inv = 1.f / sum;
        #pragma unroll
        for (int ct = 0; ct < 4; ++ct)
            #pragma unroll
            for (int j = 0; j < 4; ++j) e[ct][j] *= inv;
        if (r62 < 62 && q == (c16 >> 2)) {
            #pragma unroll
            for (int ct = 0; ct < 4; ++ct)
                if (ct == wv) {
                    #pragma unroll
                    for (int j = 0; j < 4; ++j)
                        if (j == (c16 & 3)) e[ct][j] = 1.f;
                }
        }
        float dg = 0.f;
        #pragma unroll
        for (int ct = 0; ct < 4; ++ct)
            #pragma unroll
            for (int j = 0; j < 4; ++j) dg += e[ct][j];
        dg += __shfl_xor(dg, 16);
        dg += __shfl_xor(dg, 32);
        float dri = rsqrtf(fmaxf(dg, 1.f));
        if (r62 >= 62) dri = 1.f;
        if (q == 0) degis[r62] = dri;
        __syncthreads();
        {
            unsigned short* pr = P + r62 * 72 + q * 4;
            if (r62 < 62) {
                #pragma unroll
                for (int ct = 0; ct < 4; ++ct) {
                    const float4 dm = *(const float4*)(degis + ct * 16 + q * 4);
                    ushort4 pv;
                    pv.x = f32_to_f16u(e[ct][0] * dri * dm.x);
                    pv.y = f32_to_f16u(e[ct][1] * dri * dm.y);
                    pv.z = f32_to_f16u(e[ct][2] * dri * dm.z);
                    pv.w = f32_to_f16u(e[ct][3] * dri * dm.w);
                    *(ushort4*)(pr + ct * 16) = pv;
                }
            } else {
                #pragma unroll
                for (int ct = 0; ct < 4; ++ct)
                    *(ushort4*)(pr + ct * 16) = make_ushort4(0, 0, 0, 0);
            }
        }
        __syncthreads();
        {
            f32x4 oa0 = {0.f, 0.f, 0.f, 0.f}, oa1 = {0.f, 0.f, 0.f, 0.f};
            #pragma unroll
            for (int kh = 0; kh < 2; ++kh) {
                const int chh = (kh * 4 + q) * 8;
                const f16x8 pa = *(const f16x8*)(P + r62 * 72 + chh);
                oa0 = __builtin_amdgcn_mfma_f32_16x16x32_f16(pa, zPre[kh][0], oa0, 0, 0, 0);
                oa1 = __builtin_amdgcn_mfma_f32_16x16x32_f16(pa, zPre[kh][1], oa1, 0, 0, 0);
            }
            const float* gbp = (st == 0) ? gb1 : (st == 1) ? gb2 : gb3;
            const float g0 = gbp[c16], g1 = gbp[16 + c16];
            #pragma unroll
            for (int j = 0; j < 4; ++j) {
                const int n = wv * 16 + q * 4 + j;
                unsigned short* xr = xB + n * 40 + c16;
                if (n < 62) {
                    xr[0]  = f32_to_f16u(oa0[j] + g0);
                    xr[16] = f32_to_f16u(oa1[j] + g1);
                } else { xr[0] = 0; xr[16] = 0; }
            }
        }
        __syncthreads();
        if (st == 2) break;

        {
            const float* bnbp = (st == 0) ? bnb2 : bnb3;
            const f16x8 ax = *(const f16x8*)(xB + r62 * 40 + q * 8);
            f32x4 sa[6];
            #pragma unroll
            for (int nt = 0; nt < 6; ++nt) {
                f32x4 zz = {0.f, 0.f, 0.f, 0.f};
                sa[nt] = __builtin_amdgcn_mfma_f32_16x16x32_f16(ax, wbPre[nt], zz, 0, 0, 0);
            }
            #pragma unroll
            for (int nt = 0; nt < 4; ++nt) {
                const float bb = bnbp[nt * 16 + c16];
                #pragma unroll
                for (int j = 0; j < 4; ++j) {
                    const int n = wv * 16 + q * 4 + j;
                    float th = fast_tanh(sa[nt][j] + bb);
                    if (n >= 62) th = 0.f;
                    xaH[n * 72 + nt * 16 + c16] = f32_to_f16u(th);
                }
            }
            #pragma unroll
            for (int nt = 4; nt < 6; ++nt) {
                const int o = (nt - 4) * 16 + c16;
                unsigned short zv[4];
                #pragma unroll
                for (int j = 0; j < 4; ++j) {
                    const int n = wv * 16 + q * 4 + j;
                    zv[j] = (n < 62) ? f32_to_f16u(sa[nt][j]) : (unsigned short)0;
                }
                *(ushort4*)(zB + o * 72 + wv * 16 + q * 4) =
                    make_ushort4(zv[0], zv[1], zv[2], zv[3]);
            }
        }
        __syncthreads();
    }

    // ---- maxpool3 + fc ----
    float a0 = 0.f, a1 = 0.f, a2 = 0.f;
    for (int t = tid; t < 620; t += 256) {
        const int n = t / 10, tt = t - (t / 10) * 10;
        const unsigned short* pr = xB + n * 40 + tt * 3;
        const float p = fmaxf(fmaxf(f16u_to_f32(pr[0]), f16u_to_f32(pr[1])),
                              f16u_to_f32(pr[2]));
        const float* fw = fcw + t * 3;
        a0 = fmaf(p, fw[0], a0);
        a1 = fmaf(p, fw[1], a1);
        a2 = fmaf(p, fw[2], a2);
    }
    #pragma unroll
    for (int off = 32; off; off >>= 1) {
        a0 += __shfl_down(a0, off);
        a1 += __shfl_down(a1, off);
        a2 += __shfl_down(a2, off);
    }
    float* red = degis;
    if (ln == 0) { red[wv * 3 + 0] = a0; red[wv * 3 + 1] = a1; red[wv * 3 + 2] = a2; }
    __syncthreads();
    if (tid == 0) {
        out[b * 3 + 0] = red[0] + red[3] + red[6] + red[9]  + fcb[0];
        out[b * 3 + 1] = red[1] + red[4] + red[7] + red[10] + fcb[1];
        out[b * 3 + 2] = red[2] + red[5] + red[8] + red[11] + fcb[2];
    }
}

// ============================== launcher ====================================
extern "C" void kernel_launch(void* const* d_in, const int* in_sizes, int n_in,
                              void* d_out, int out_size, void* d_ws, size_t ws_size,
                              hipStream_t stream) {
    const float* x     = (const float*)d_in[0];
    const float* convw = (const float*)d_in[1];
    const float* convb = (const float*)d_in[2];
    const float* bnw1  = (const float*)d_in[3];
    const float* bnb1  = (const float*)d_in[4];
    const float* gw1   = (const float*)d_in[5];
    const float* gb1   = (const float*)d_in[6];
    const float* bnw2  = (const float*)d_in[7];
    const float* bnb2  = (const float*)d_in[8];
    const float* gw2   = (const float*)d_in[9];
    const float* gb2   = (const float*)d_in[10];
    const float* bnw3  = (const float*)d_in[11];
    const float* bnb3  = (const float*)d_in[12];
    const float* gw3   = (const float*)d_in[13];
    const float* gb3   = (const float*)d_in[14];
    const float* fcw   = (const float*)d_in[15];
    const float* fcb   = (const float*)d_in[16];

    unsigned short* wp = (unsigned short*)d_ws;
    float4* part = (float4*)((char*)d_ws + PART_OFF);   // 50.3 MB

    prepack_kernel<<<392, 256, 0, stream>>>(bnw1, gw1, convw, bnw2, gw2,
                                            bnw3, gw3, wp);
    conv_g1_kernel<<<2048, 256, 0, stream>>>(x, convb, wp, part);
    sogc_tail_kernel<<<1024, 256, 0, stream>>>(wp, part, bnb1, gb1, gb2, gb3,
                                               bnb2, bnb3, fcw, fcb,
                                               (float*)d_out);
}

// Round 16
// 73.518 us; speedup vs baseline: 1.2486x; 1.2486x over previous
//
#include <hip/hip_runtime.h>
#include <math.h>

// ---------------------------------------------------------------------------
// B=1024. R16 = R13 reverted (best-known: 73.5 us). Single mega-kernel:
//   conv(MFMA 32x32x16_f16, b128 tap loads) + pool -> Xcol (XOR-swizzled LDS)
//   G1 (16x16x32_f16, K-permuted k'=pj*32+s, 1-deep B pipeline from global)
//   tail: 3x SOGC all-fp16-MFMA, transposed-S softmax (row-per-lane, 2 shfl)
//   reshape fact: node n = (c*62+r)/32, feature f = ((c*62+r)%32)*15 + j
// ---------------------------------------------------------------------------

typedef _Float16 f16x8 __attribute__((ext_vector_type(8)));
typedef float    f32x4  __attribute__((ext_vector_type(4)));
typedef float    f32x16 __attribute__((ext_vector_type(16)));

__device__ __forceinline__ unsigned short f32_to_f16u(float f) {
    const _Float16 h = (_Float16)f;
    return __builtin_bit_cast(unsigned short, h);
}
__device__ __forceinline__ float f16u_to_f32(unsigned short u) {
    return (float)__builtin_bit_cast(_Float16, u);
}
__device__ __forceinline__ float fast_tanh(float v) {
    v = fminf(fmaxf(v, -15.f), 15.f);
    const float ex = __expf(2.f * v);
    return (ex - 1.f) / (ex + 1.f);
}

// ws layout (u16 units):
//   [0, 49152)        G1 W fp16, 16 kc (kc=15 zeros), B-frag order k'=pj*32+s
//   [92160, 93696)    conv W frags fp16 (32x32 shape, 3 chunks)
//   [94208, 100352)   stage2 (3072) + stage3 (3072) B-frag fp16 [col 96][k 32]

// ============================ prepack ======================================
__global__ __launch_bounds__(256) void prepack_kernel(
    const float* __restrict__ bnw1, const float* __restrict__ gw1,
    const float* __restrict__ cw,
    const float* __restrict__ bnw2, const float* __restrict__ gw2,
    const float* __restrict__ bnw3, const float* __restrict__ gw3,
    unsigned short* __restrict__ wp)
{
    const int idx = blockIdx.x * 256 + threadIdx.x;   // grid covers 100352
    if (idx < 49152) {
        const int kc = idx / 3072, r = idx - kc * 3072;
        const int q = r / 768, r2 = r - q * 768;
        const int col = r2 >> 3, j = r2 & 7;
        float w = 0.f;
        if (kc < 15) {
            const int s = q * 8 + j;
            const int ko = s * 15 + kc;
            w = (col < 64) ? bnw1[ko * 64 + col] : gw1[ko * 32 + (col - 64)];
        }
        wp[idx] = f32_to_f16u(w);
    } else if (idx >= 92160 && idx < 93696) {
        const int e = idx - 92160;
        const int c = e >> 9, l = (e >> 3) & 63, j = e & 7;
        const int ch = l & 31, dio = l >> 5;
        const int di = (c < 2) ? (2 * c + dio) : (4 + dio);
        const float w = (j < 5 && di < 5) ? cw[ch * 25 + di * 5 + j] : 0.f;
        wp[idx] = f32_to_f16u(w);
    } else if (idx >= 94208 && idx < 100352) {
        const int e2 = idx - 94208;
        const int s = e2 / 3072, r = e2 - s * 3072;
        const int col = r >> 5, k = r & 31;
        const float* bnw = s ? bnw3 : bnw2;
        const float* gw  = s ? gw3  : gw2;
        const float w = (col < 64) ? bnw[k * 64 + col] : gw[k * 32 + (col - 64)];
        wp[idx] = f32_to_f16u(w);
    }
}

// ============================= mega kernel =================================
__global__ __launch_bounds__(256, 4) void mega_kernel(
    const float* __restrict__ x,     // (B,66,64)
    const float* __restrict__ cb,    // (32,)
    const unsigned short* __restrict__ wp,
    const float* __restrict__ bnb1,  const float* __restrict__ gb1,
    const float* __restrict__ bnb2,  const float* __restrict__ gb2,
    const float* __restrict__ bnb3,  const float* __restrict__ gb3,
    const float* __restrict__ fcw,   const float* __restrict__ fcb,
    float* __restrict__ out)         // (B,3)
{
    // conv phase: xb @0 (10880 B, 68x80 f16) | Xcol @10880 (16384 B, 64x128)
    // tail phase (overlays): xaH u16@0 [64][72] | zB u16@4608 [32][72] |
    //   P u16@6912 [64][72] | xB u16@11520 [64][40] | degis @byte 28160
    __shared__ __align__(16) char lds[28416];
    unsigned short* xb   = (unsigned short*)lds;
    unsigned short* Xcol = (unsigned short*)(lds + 10880);
    unsigned short* xaH  = (unsigned short*)lds;
    unsigned short* zB   = xaH + 4608;
    unsigned short* P    = xaH + 6912;
    unsigned short* xB   = xaH + 11520;
    float* degis = (float*)(lds + 28160);

    const int b = blockIdx.x;
    const int tid = threadIdx.x;
    const int wv = tid >> 6, ln = tid & 63;

    // ---- phase A: x -> f16 LDS; zero pads ----
    const float4* xg = (const float4*)(x + (size_t)b * 4224);
    for (int idx = tid; idx < 1056; idx += 256) {
        const float4 v = xg[idx];
        const int row = idx >> 4, c4 = idx & 15;
        short4 s;
        s.x = (short)f32_to_f16u(v.x);
        s.y = (short)f32_to_f16u(v.y);
        s.z = (short)f32_to_f16u(v.z);
        s.w = (short)f32_to_f16u(v.w);
        *(short4*)(xb + row * 80 + c4 * 4) = s;
    }
    for (int idx = tid; idx < 544; idx += 256) {        // cols 64..79 zero (68 rows)
        const int row = idx >> 3, w = idx & 7;
        ((unsigned int*)(xb + row * 80 + 64))[w] = 0u;
    }
    if (tid < 64) {                                     // rows 66,67 cols 0..63
        const int row = 66 + (tid >> 5), w = tid & 31;
        ((unsigned int*)(xb + row * 80))[w] = 0u;
    }
    if (tid < 128)                                      // Xcol rows 62,63 zero
        ((unsigned int*)(Xcol + 62 * 128))[tid] = 0u;
    __syncthreads();

    // conv lane roles: ch=l&31, hi=l>>5; A: m=l&15, rp=(l>>4)&1, dio=l>>5
    const int m = ln & 15, rp = (ln >> 4) & 1, dio = ln >> 5;
    const int ch = ln & 31, hi = ln >> 5;
    f16x8 Wc[3];
    #pragma unroll
    for (int c = 0; c < 3; ++c)
        Wc[c] = *(const f16x8*)(wp + 92160 + c * 512 + ln * 8);
    const float cbv = cb[ch];
    const f32x16 z16 = {};          // persistent zero accumulator

    // G1 lane roles: rt = l&15, q = l>>4
    const int rt = ln & 15, q = ln >> 4;
    f32x4 acc[6];
    #pragma unroll
    for (int nt = 0; nt < 6; ++nt) acc[nt] = (f32x4){0.f, 0.f, 0.f, 0.f};

    for (int pjg = 0; pjg < 4; ++pjg) {
        const int j0 = pjg * 16;
        // prefetch g=0 G1 B-frags (independent of Xcol; hidden under conv)
        f16x8 Bp[6];
        {
            const unsigned short* wB = wp + (pjg * 4) * 3072 + q * 768 + rt * 8;
            #pragma unroll
            for (int nt = 0; nt < 6; ++nt) Bp[nt] = *(const f16x8*)(wB + nt * 128);
        }
        // ---- conv: 31 row-pairs, pooled cols pjg*4 + {0..3} -> Xcol ----
        #pragma unroll 4
        for (int p = wv; p < 31; p += 4) {
            const int r0 = 2 * p;
            const unsigned short* base = xb + (r0 + rp + dio) * 80 + j0 + m;
            f32x16 a32;
            #pragma unroll
            for (int c = 0; c < 3; ++c) {
                // taps 0..4 contiguous; elems 5..7 finite x values * zero W.
                // misaligned (2B) LDS b128 read — gfx950 unaligned DS access.
                const f16x8 Af = *(const f16x8*)(base + c * 160);
                a32 = __builtin_amdgcn_mfma_f32_32x32x16_f16(
                          Af, Wc[c], (c == 0) ? z16 : a32, 0, 0, 0);
            }
            #pragma unroll
            for (int i = 0; i < 4; ++i) {
                const int t = 2 * i + hi;
                const int rpo = t >> 2, g = t & 3;
                float v = fmaxf(fmaxf(a32[4 * i], a32[4 * i + 1]),
                                fmaxf(a32[4 * i + 2], a32[4 * i + 3])) + cbv;
                v = fmaxf(v, 0.f);
                if (!(pjg == 3 && g == 3)) {
                    const int row = r0 + rpo;
                    const int tt = ch * 62 + row;        // n = tt/32, s = tt%32
                    const int n = tt >> 5, sf = tt & 31;
                    Xcol[n * 128 + ((g * 32 + sf) ^ ((n & 7) << 3))] =
                        f32_to_f16u(v);
                }
            }
        }
        __syncthreads();
        // ---- G1: kc = pjg*4 + g (kc=15 -> zero W); 1-deep B pipeline ----
        {
            const int row = wv * 16 + rt;
            #pragma unroll
            for (int g = 0; g < 4; ++g) {
                f16x8 Bn[6];
                #pragma unroll
                for (int nt = 0; nt < 6; ++nt)
                    Bn[nt] = (g < 3)
                        ? *(const f16x8*)(wp + (pjg * 4 + g + 1) * 3072
                                          + q * 768 + nt * 128 + rt * 8)
                        : Bp[nt];
                const f16x8 A = *(const f16x8*)(
                    Xcol + row * 128 + (((g * 4 + q) ^ (row & 7)) << 3));
                #pragma unroll
                for (int nt = 0; nt < 6; ++nt)
                    acc[nt] = __builtin_amdgcn_mfma_f32_16x16x32_f16(A, Bp[nt], acc[nt], 0, 0, 0);
                #pragma unroll
                for (int nt = 0; nt < 6; ++nt) Bp[nt] = Bn[nt];
            }
        }
        __syncthreads();
    }

    // ---- G1 epilogue -> tail LDS buffers (conv buffers dead) ----
    {
        const int rq = wv * 4 + q;
        #pragma unroll
        for (int nt = 0; nt < 4; ++nt) {
            const float bb = bnb1[nt * 16 + rt];
            #pragma unroll
            for (int j = 0; j < 4; ++j) {
                const int r = rq * 4 + j;
                float th = fast_tanh(acc[nt][j] + bb);
                if (r >= 62) th = 0.f;
                xaH[r * 72 + nt * 16 + rt] = f32_to_f16u(th);
            }
        }
        #pragma unroll
        for (int nt = 4; nt < 6; ++nt) {
            const int o = (nt - 4) * 16 + rt;
            unsigned short zv[4];
            #pragma unroll
            for (int j = 0; j < 4; ++j) {
                const int r = rq * 4 + j;
                zv[j] = (r < 62) ? f32_to_f16u(acc[nt][j]) : (unsigned short)0;
            }
            *(ushort4*)(zB + o * 72 + rq * 4) =
                make_ushort4(zv[0], zv[1], zv[2], zv[3]);
        }
    }
    __syncthreads();

    // ---- tail: 3x SOGC all-fp16-MFMA, transposed-S softmax ----
    const int c16 = ln & 15;
    const int r62 = wv * 16 + c16;          // this lane's S row
    const unsigned short* wstg = wp + 94208;

    #pragma unroll 1
    for (int st = 0; st < 3; ++st) {
        // zB is stable this whole stage: hoist PV z-frag reads to stage top
        f16x8 zPre[2][2];
        #pragma unroll
        for (int kh = 0; kh < 2; ++kh) {
            const int chh = (kh * 4 + q) * 8;
            zPre[kh][0] = *(const f16x8*)(zB + c16 * 72 + chh);
            zPre[kh][1] = *(const f16x8*)(zB + (16 + c16) * 72 + chh);
        }
        // S^T tiles: sacc[ct][j] = S[r62][ct*16 + q*4 + j]
        f32x4 sacc[4];
        #pragma unroll
        for (int ct = 0; ct < 4; ++ct) sacc[ct] = (f32x4){0.f, 0.f, 0.f, 0.f};
        const int arow = r62 * 72;
        #pragma unroll
        for (int kh = 0; kh < 2; ++kh) {
            const int chh = (kh * 4 + q) * 8;
            const f16x8 Bw = *(const f16x8*)(xaH + arow + chh);   // B: cols of wv-block
            #pragma unroll
            for (int ct = 0; ct < 4; ++ct) {
                const f16x8 Act = *(const f16x8*)(xaH + (ct * 16 + c16) * 72 + chh);
                sacc[ct] = __builtin_amdgcn_mfma_f32_16x16x32_f16(Act, Bw, sacc[ct], 0, 0, 0);
            }
        }
        // prefetch next-stage gemm weights (global; hidden under softmax)
        f16x8 wbPre[6];
        if (st < 2) {
            const unsigned short* wsB = wstg + st * 3072;
            #pragma unroll
            for (int nt = 0; nt < 6; ++nt)
                wbPre[nt] = *(const f16x8*)(wsB + (nt * 16 + c16) * 32 + q * 8);
        }
        // ---- row softmax, fully lane-local + 2 shfl rounds over q ----
        float mx = -1e30f;
        #pragma unroll
        for (int ct = 0; ct < 4; ++ct)
            #pragma unroll
            for (int j = 0; j < 4; ++j) mx = fmaxf(mx, sacc[ct][j]);
        mx = fmaxf(mx, __shfl_xor(mx, 16));
        mx = fmaxf(mx, __shfl_xor(mx, 32));
        float e[4][4];
        float sum = 0.f;
        #pragma unroll
        for (int ct = 0; ct < 4; ++ct)
            #pragma unroll
            for (int j = 0; j < 4; ++j) {
                float v = __expf(sacc[ct][j] - mx);
                if (ct == 3 && j >= 2 && q == 3) v = 0.f;    // cols 62,63
                e[ct][j] = v; sum += v;
            }
        sum += __shfl_xor(sum, 16);
        sum += __shfl_xor(sum, 32);
        const float inv = 1.f / sum;
        #pragma unroll
        for (int ct = 0; ct < 4; ++ct)
            #pragma unroll
            for (int j = 0; j < 4; ++j) e[ct][j] *= inv;
        // diag <- 1 at col == r62 (ct==wv, q==c16>>2, j==c16&3)
        if (r62 < 62 && q == (c16 >> 2)) {
            #pragma unroll
            for (int ct = 0; ct < 4; ++ct)
                if (ct == wv) {
                    #pragma unroll
                    for (int j = 0; j < 4; ++j)
                        if (j == (c16 & 3)) e[ct][j] = 1.f;
                }
        }
        // degree
        float dg = 0.f;
        #pragma unroll
        for (int ct = 0; ct < 4; ++ct)
            #pragma unroll
            for (int j = 0; j < 4; ++j) dg += e[ct][j];
        dg += __shfl_xor(dg, 16);
        dg += __shfl_xor(dg, 32);
        float dri = rsqrtf(fmaxf(dg, 1.f));
        if (r62 >= 62) dri = 1.f;
        if (q == 0) degis[r62] = dri;
        __syncthreads();
        // ---- P[r62][*] = dri * e * degis[col], 4x ushort4 ----
        {
            unsigned short* pr = P + r62 * 72 + q * 4;
            if (r62 < 62) {
                #pragma unroll
                for (int ct = 0; ct < 4; ++ct) {
                    const float4 dm = *(const float4*)(degis + ct * 16 + q * 4);
                    ushort4 pv;
                    pv.x = f32_to_f16u(e[ct][0] * dri * dm.x);
                    pv.y = f32_to_f16u(e[ct][1] * dri * dm.y);
                    pv.z = f32_to_f16u(e[ct][2] * dri * dm.z);
                    pv.w = f32_to_f16u(e[ct][3] * dri * dm.w);
                    *(ushort4*)(pr + ct * 16) = pv;
                }
            } else {
                #pragma unroll
                for (int ct = 0; ct < 4; ++ct)
                    *(ushort4*)(pr + ct * 16) = make_ushort4(0, 0, 0, 0);
            }
        }
        __syncthreads();
        // ---- O = P @ z + gb -> xB ----
        {
            f32x4 oa0 = {0.f, 0.f, 0.f, 0.f}, oa1 = {0.f, 0.f, 0.f, 0.f};
            #pragma unroll
            for (int kh = 0; kh < 2; ++kh) {
                const int chh = (kh * 4 + q) * 8;
                const f16x8 pa = *(const f16x8*)(P + (wv * 16 + c16) * 72 + chh);
                oa0 = __builtin_amdgcn_mfma_f32_16x16x32_f16(pa, zPre[kh][0], oa0, 0, 0, 0);
                oa1 = __builtin_amdgcn_mfma_f32_16x16x32_f16(pa, zPre[kh][1], oa1, 0, 0, 0);
            }
            const float* gbp = (st == 0) ? gb1 : (st == 1) ? gb2 : gb3;
            const float g0 = gbp[c16], g1 = gbp[16 + c16];
            #pragma unroll
            for (int j = 0; j < 4; ++j) {
                const int n = wv * 16 + q * 4 + j;
                unsigned short* xr = xB + n * 40 + c16;
                if (n < 62) {
                    xr[0]  = f32_to_f16u(oa0[j] + g0);
                    xr[16] = f32_to_f16u(oa1[j] + g1);
                } else { xr[0] = 0; xr[16] = 0; }
            }
        }
        __syncthreads();
        if (st == 2) break;

        // ---- stage gemms: xa' = tanh(x@bnw+bnb), z' = x@gw ----
        {
            const float* bnbp = (st == 0) ? bnb2 : bnb3;
            const f16x8 ax = *(const f16x8*)(xB + (wv * 16 + c16) * 40 + q * 8);
            f32x4 sa[6];
            #pragma unroll
            for (int nt = 0; nt < 6; ++nt) {
                f32x4 zz = {0.f, 0.f, 0.f, 0.f};
                sa[nt] = __builtin_amdgcn_mfma_f32_16x16x32_f16(ax, wbPre[nt], zz, 0, 0, 0);
            }
            #pragma unroll
            for (int nt = 0; nt < 4; ++nt) {
                const float bb = bnbp[nt * 16 + c16];
                #pragma unroll
                for (int j = 0; j < 4; ++j) {
                    const int n = wv * 16 + q * 4 + j;
                    float th = fast_tanh(sa[nt][j] + bb);
                    if (n >= 62) th = 0.f;
                    xaH[n * 72 + nt * 16 + c16] = f32_to_f16u(th);
                }
            }
            #pragma unroll
            for (int nt = 4; nt < 6; ++nt) {
                const int o = (nt - 4) * 16 + c16;
                unsigned short zv[4];
                #pragma unroll
                for (int j = 0; j < 4; ++j) {
                    const int n = wv * 16 + q * 4 + j;
                    zv[j] = (n < 62) ? f32_to_f16u(sa[nt][j]) : (unsigned short)0;
                }
                *(ushort4*)(zB + o * 72 + wv * 16 + q * 4) =
                    make_ushort4(zv[0], zv[1], zv[2], zv[3]);
            }
        }
        __syncthreads();
    }

    // ---- maxpool3 + fc ----
    float a0 = 0.f, a1 = 0.f, a2 = 0.f;
    for (int t = tid; t < 620; t += 256) {
        const int n = t / 10, tt = t - (t / 10) * 10;
        const unsigned short* pr = xB + n * 40 + tt * 3;
        const float p = fmaxf(fmaxf(f16u_to_f32(pr[0]), f16u_to_f32(pr[1])),
                              f16u_to_f32(pr[2]));
        const float* fw = fcw + t * 3;
        a0 = fmaf(p, fw[0], a0);
        a1 = fmaf(p, fw[1], a1);
        a2 = fmaf(p, fw[2], a2);
    }
    #pragma unroll
    for (int off = 32; off; off >>= 1) {
        a0 += __shfl_down(a0, off);
        a1 += __shfl_down(a1, off);
        a2 += __shfl_down(a2, off);
    }
    float* red = degis;
    if (ln == 0) { red[wv * 3 + 0] = a0; red[wv * 3 + 1] = a1; red[wv * 3 + 2] = a2; }
    __syncthreads();
    if (tid == 0) {
        out[b * 3 + 0] = red[0] + red[3] + red[6] + red[9]  + fcb[0];
        out[b * 3 + 1] = red[1] + red[4] + red[7] + red[10] + fcb[1];
        out[b * 3 + 2] = red[2] + red[5] + red[8] + red[11] + fcb[2];
    }
}

// ============================== launcher ====================================
extern "C" void kernel_launch(void* const* d_in, const int* in_sizes, int n_in,
                              void* d_out, int out_size, void* d_ws, size_t ws_size,
                              hipStream_t stream) {
    const float* x     = (const float*)d_in[0];
    const float* convw = (const float*)d_in[1];
    const float* convb = (const float*)d_in[2];
    const float* bnw1  = (const float*)d_in[3];
    const float* bnb1  = (const float*)d_in[4];
    const float* gw1   = (const float*)d_in[5];
    const float* gb1   = (const float*)d_in[6];
    const float* bnw2  = (const float*)d_in[7];
    const float* bnb2  = (const float*)d_in[8];
    const float* gw2   = (const float*)d_in[9];
    const float* gb2   = (const float*)d_in[10];
    const float* bnw3  = (const float*)d_in[11];
    const float* bnb3  = (const float*)d_in[12];
    const float* gw3   = (const float*)d_in[13];
    const float* gb3   = (const float*)d_in[14];
    const float* fcw   = (const float*)d_in[15];
    const float* fcb   = (const float*)d_in[16];

    unsigned short* wp = (unsigned short*)d_ws;   // 200,704 B used

    prepack_kernel<<<392, 256, 0, stream>>>(bnw1, gw1, convw, bnw2, gw2,
                                            bnw3, gw3, wp);
    mega_kernel<<<1024, 256, 0, stream>>>(x, convb, wp, bnb1, gb1,
                                          bnb2, gb2, bnb3, gb3,
                                          fcw, fcb, (float*)d_out);
}